// Round 1
// baseline (144.501 us; speedup 1.0000x reference)
//
#include <hip/hip_runtime.h>

// Level geometry (hardcoded from the reference setup_inputs()):
// shapes: (128,1,334,200),(128,1,167,100),(128,1,84,50),(128,1,42,25),(128,1,21,13)
#define NLEV 5
#define BATCH 128
#define NBOX 64

__device__ __constant__ int c_H[NLEV] = {334, 167, 84, 42, 21};
__device__ __constant__ int c_W[NLEV] = {200, 100, 50, 25, 13};
__device__ __constant__ int c_N[NLEV] = {8550400, 2137600, 537600, 134400, 34944};

// ---------------------------------------------------------------- sum kernel
// Sums each level's h tensor into sums[lev] (double), hierarchical reduction.
__global__ __launch_bounds__(256) void sum_kernel(
    const float* __restrict__ h0, const float* __restrict__ h1,
    const float* __restrict__ h2, const float* __restrict__ h3,
    const float* __restrict__ h4, double* __restrict__ sums) {
  const int lev = blockIdx.y;
  const float* p;
  switch (lev) {
    case 0: p = h0; break;
    case 1: p = h1; break;
    case 2: p = h2; break;
    case 3: p = h3; break;
    default: p = h4; break;
  }
  const int n4 = c_N[lev] >> 2;  // all N divisible by 4
  const float4* __restrict__ p4 = (const float4*)p;

  double acc = 0.0;
  for (int i = blockIdx.x * blockDim.x + threadIdx.x; i < n4;
       i += gridDim.x * blockDim.x) {
    float4 v = p4[i];
    acc += (double)v.x;
    acc += (double)v.y;
    acc += (double)v.z;
    acc += (double)v.w;
  }
  // wave (64-lane) reduction
  for (int off = 32; off > 0; off >>= 1) acc += __shfl_down(acc, off, 64);
  __shared__ double s_part[4];
  const int wave = threadIdx.x >> 6;
  const int lane = threadIdx.x & 63;
  if (lane == 0) s_part[wave] = acc;
  __syncthreads();
  if (threadIdx.x == 0) {
    double tot = (s_part[0] + s_part[1]) + (s_part[2] + s_part[3]);
    atomicAdd(&sums[lev], tot);
  }
}

// ------------------------------------------------------------- cover kernel
// One block per (batch, level). Counts pixels covered by the union of boxes
// via per-row 256-bit column masks (W <= 200).
__device__ inline unsigned long long maskn(int n) {
  // bits [0, n), n clamped to [0,64]
  return (n >= 64) ? ~0ull : ((1ull << n) - 1ull);
}
__device__ inline unsigned long long rangemask(int x1, int x2, int base) {
  int lo = min(max(x1 - base, 0), 64);
  int hi = min(max(x2 - base, 0), 64);
  return maskn(hi) & ~maskn(lo);
}

__global__ __launch_bounds__(256) void cover_kernel(
    const float* __restrict__ boxes, const int* __restrict__ dimx,
    const int* __restrict__ dimy, unsigned long long* __restrict__ counts) {
  const int lev = blockIdx.y;
  const int b = blockIdx.x;
  const int H = c_H[lev], W = c_W[lev];
  // scale computed in double, cast to f32 (matches numpy weak-scalar promotion)
  const float sx = (float)((double)W / (double)dimx[0]);
  const float sy = (float)((double)H / (double)dimy[0]);

  __shared__ int s_x1[NBOX], s_x2[NBOX], s_y1[NBOX], s_y2[NBOX];
  const int t = threadIdx.x;
  if (t < NBOX) {
    const float* bp = boxes + ((size_t)b * NBOX + t) * 4;
    // round-half-even == rintf (default rounding mode), then clip like ref
    float fx1 = rintf(bp[0] * sx);
    float fy1 = rintf(bp[1] * sy);
    float fx2 = rintf(bp[2] * sx);
    float fy2 = rintf(bp[3] * sy);
    int x1 = (int)fminf(fmaxf(fx1, 0.0f), (float)(W - 1));
    int y1 = (int)fminf(fmaxf(fy1, 0.0f), (float)(H - 1));
    int x2 = (int)fminf(fmaxf(fx2, 0.0f), (float)W);
    int y2 = (int)fminf(fmaxf(fy2, 0.0f), (float)H);
    if (!((x2 > x1) && (y2 > y1))) { y1 = 0; y2 = 0; }  // invalid -> empty
    s_x1[t] = x1; s_x2[t] = x2; s_y1[t] = y1; s_y2[t] = y2;
  }
  __syncthreads();

  int local = 0;
  for (int h = t; h < H; h += blockDim.x) {
    unsigned long long w0 = 0, w1 = 0, w2 = 0, w3 = 0;
    for (int m = 0; m < NBOX; ++m) {
      if (h >= s_y1[m] && h < s_y2[m]) {
        int x1 = s_x1[m], x2 = s_x2[m];
        w0 |= rangemask(x1, x2, 0);
        w1 |= rangemask(x1, x2, 64);
        w2 |= rangemask(x1, x2, 128);
        w3 |= rangemask(x1, x2, 192);
      }
    }
    local += __popcll(w0) + __popcll(w1) + __popcll(w2) + __popcll(w3);
  }
  for (int off = 32; off > 0; off >>= 1) local += __shfl_down(local, off, 64);
  __shared__ int s_cnt[4];
  const int wave = threadIdx.x >> 6;
  const int lane = threadIdx.x & 63;
  if (lane == 0) s_cnt[wave] = local;
  __syncthreads();
  if (threadIdx.x == 0) {
    unsigned long long tot =
        (unsigned long long)(s_cnt[0] + s_cnt[1] + s_cnt[2] + s_cnt[3]);
    atomicAdd(&counts[lev], tot);
  }
}

// -------------------------------------------------------------- final kernel
__global__ void final_kernel(const double* __restrict__ sums,
                             const unsigned long long* __restrict__ counts,
                             float* __restrict__ out) {
  if (threadIdx.x == 0 && blockIdx.x == 0) {
    double acc = 0.0;
    for (int l = 0; l < NLEV; ++l) {
      double tn = (double)BATCH * (double)c_H[l] * (double)c_W[l];
      double d = sums[l] / tn - (double)counts[l] / tn;
      acc += d * d;
    }
    out[0] = (float)(acc / (double)NLEV);
  }
}

extern "C" void kernel_launch(void* const* d_in, const int* in_sizes, int n_in,
                              void* d_out, int out_size, void* d_ws,
                              size_t ws_size, hipStream_t stream) {
  const float* h0 = (const float*)d_in[0];
  const float* h1 = (const float*)d_in[1];
  const float* h2 = (const float*)d_in[2];
  const float* h3 = (const float*)d_in[3];
  const float* h4 = (const float*)d_in[4];
  const float* boxes = (const float*)d_in[5];
  const int* dimx = (const int*)d_in[6];
  const int* dimy = (const int*)d_in[7];

  double* sums = (double*)d_ws;                              // 5 doubles
  unsigned long long* counts = (unsigned long long*)((char*)d_ws + 64);  // 5 u64

  hipMemsetAsync(d_ws, 0, 128, stream);

  dim3 sgrid(512, NLEV);
  sum_kernel<<<sgrid, 256, 0, stream>>>(h0, h1, h2, h3, h4, sums);

  dim3 cgrid(BATCH, NLEV);
  cover_kernel<<<cgrid, 256, 0, stream>>>(boxes, dimx, dimy, counts);

  final_kernel<<<1, 64, 0, stream>>>(sums, counts, (float*)d_out);
}

// Round 2
// 110.288 us; speedup vs baseline: 1.3102x; 1.3102x over previous
//
#include <hip/hip_runtime.h>

// Level geometry (hardcoded from the reference setup_inputs()):
// shapes: (128,1,334,200),(128,1,167,100),(128,1,84,50),(128,1,42,25),(128,1,21,13)
#define NLEV 5
#define BATCH 128
#define NBOX 64

__device__ __constant__ int c_H[NLEV] = {334, 167, 84, 42, 21};
__device__ __constant__ int c_W[NLEV] = {200, 100, 50, 25, 13};
// element counts / 4 (all divisible by 4)
__device__ __constant__ int c_N4[NLEV] = {2137600, 534400, 134400, 33600, 8736};
// sum-block bases per level (blocks ∝ level size): 512,128,32,16,8
__device__ __constant__ int c_sb_base[NLEV + 1] = {0, 512, 640, 672, 688, 696};

#define NSUMB 696
#define NCOVB (NLEV * BATCH)   // 640
#define NBLOCKS (NSUMB + NCOVB)

// ws layout: [0, 696) doubles = sum partials; then 640 uints = cover partials
#define COV_OFF_BYTES (NSUMB * 8)   // 5568, 8-aligned

__device__ inline unsigned long long maskn(int n) {
  return (n >= 64) ? ~0ull : ((1ull << n) - 1ull);
}
__device__ inline unsigned long long rangemask(int x1, int x2, int base) {
  int lo = min(max(x1 - base, 0), 64);
  int hi = min(max(x2 - base, 0), 64);
  return maskn(hi) & ~maskn(lo);
}

// --------------------------------------------------------------- fused kernel
// Blocks [0, NSUMB): per-level sum partials (double, one slot per block).
// Blocks [NSUMB, NBLOCKS): per-(level,batch) coverage count (one slot/block).
__global__ __launch_bounds__(256) void fused_kernel(
    const float* __restrict__ h0, const float* __restrict__ h1,
    const float* __restrict__ h2, const float* __restrict__ h3,
    const float* __restrict__ h4, const float* __restrict__ boxes,
    const int* __restrict__ dimx, const int* __restrict__ dimy,
    void* __restrict__ ws) {
  double* __restrict__ sum_part = (double*)ws;
  unsigned int* __restrict__ cov_part =
      (unsigned int*)((char*)ws + COV_OFF_BYTES);
  const int blk = blockIdx.x;
  const int t = threadIdx.x;

  if (blk < NSUMB) {
    // ---- sum role ----
    int lev = 0;
    while (blk >= c_sb_base[lev + 1]) ++lev;
    const int lblk = blk - c_sb_base[lev];
    const int nblk = c_sb_base[lev + 1] - c_sb_base[lev];
    const float* p;
    switch (lev) {
      case 0: p = h0; break;
      case 1: p = h1; break;
      case 2: p = h2; break;
      case 3: p = h3; break;
      default: p = h4; break;
    }
    const float4* __restrict__ p4 = (const float4*)p;
    const int n4 = c_N4[lev];
    const int stride = nblk * 256;

    double acc = 0.0;
    for (int i = lblk * 256 + t; i < n4; i += stride) {
      float4 v = p4[i];
      acc += (double)v.x;
      acc += (double)v.y;
      acc += (double)v.z;
      acc += (double)v.w;
    }
    for (int off = 32; off > 0; off >>= 1) acc += __shfl_down(acc, off, 64);
    __shared__ double s_part[4];
    const int wave = t >> 6, lane = t & 63;
    if (lane == 0) s_part[wave] = acc;
    __syncthreads();
    if (t == 0)
      sum_part[blk] = (s_part[0] + s_part[1]) + (s_part[2] + s_part[3]);
  } else {
    // ---- cover role ----
    const int cb = blk - NSUMB;
    const int lev = cb >> 7;      // cb / BATCH
    const int b = cb & 127;       // cb % BATCH
    const int H = c_H[lev], W = c_W[lev];
    const float sx = (float)((double)W / (double)dimx[0]);
    const float sy = (float)((double)H / (double)dimy[0]);

    __shared__ int s_x1[NBOX], s_x2[NBOX], s_y1[NBOX], s_y2[NBOX];
    if (t < NBOX) {
      const float* bp = boxes + ((size_t)b * NBOX + t) * 4;
      float fx1 = rintf(bp[0] * sx);   // round-half-even == default rintf
      float fy1 = rintf(bp[1] * sy);
      float fx2 = rintf(bp[2] * sx);
      float fy2 = rintf(bp[3] * sy);
      int x1 = (int)fminf(fmaxf(fx1, 0.0f), (float)(W - 1));
      int y1 = (int)fminf(fmaxf(fy1, 0.0f), (float)(H - 1));
      int x2 = (int)fminf(fmaxf(fx2, 0.0f), (float)W);
      int y2 = (int)fminf(fmaxf(fy2, 0.0f), (float)H);
      if (!((x2 > x1) && (y2 > y1))) { y1 = 0; y2 = 0; }  // invalid -> empty
      s_x1[t] = x1; s_x2[t] = x2; s_y1[t] = y1; s_y2[t] = y2;
    }
    __syncthreads();

    int local = 0;
    for (int h = t; h < H; h += 256) {
      unsigned long long w0 = 0, w1 = 0, w2 = 0, w3 = 0;
      for (int m = 0; m < NBOX; ++m) {
        if (h >= s_y1[m] && h < s_y2[m]) {
          int x1 = s_x1[m], x2 = s_x2[m];
          w0 |= rangemask(x1, x2, 0);
          w1 |= rangemask(x1, x2, 64);
          w2 |= rangemask(x1, x2, 128);
          w3 |= rangemask(x1, x2, 192);
        }
      }
      local += __popcll(w0) + __popcll(w1) + __popcll(w2) + __popcll(w3);
    }
    for (int off = 32; off > 0; off >>= 1) local += __shfl_down(local, off, 64);
    __shared__ int s_cnt[4];
    const int wave = t >> 6, lane = t & 63;
    if (lane == 0) s_cnt[wave] = local;
    __syncthreads();
    if (t == 0)
      cov_part[cb] =
          (unsigned int)(s_cnt[0] + s_cnt[1] + s_cnt[2] + s_cnt[3]);
  }
}

// --------------------------------------------------------------- final kernel
// One block, 5 waves; wave w reduces level w's partials.
__global__ __launch_bounds__(320) void final_kernel(
    const void* __restrict__ ws, float* __restrict__ out) {
  const double* __restrict__ sum_part = (const double*)ws;
  const unsigned int* __restrict__ cov_part =
      (const unsigned int*)((const char*)ws + COV_OFF_BYTES);
  const int wave = threadIdx.x >> 6;
  const int lane = threadIdx.x & 63;
  __shared__ double s_loss[NLEV];

  const int sb0 = c_sb_base[wave], sb1 = c_sb_base[wave + 1];
  double s = 0.0;
  for (int i = sb0 + lane; i < sb1; i += 64) s += sum_part[i];
  unsigned int c = 0;
  for (int i = lane; i < BATCH; i += 64) c += cov_part[wave * BATCH + i];
  for (int off = 32; off > 0; off >>= 1) {
    s += __shfl_down(s, off, 64);
    c += __shfl_down(c, off, 64);
  }
  if (lane == 0) {
    double tn = (double)BATCH * (double)c_H[wave] * (double)c_W[wave];
    double d = s / tn - (double)c / tn;
    s_loss[wave] = d * d;
  }
  __syncthreads();
  if (threadIdx.x == 0) {
    double acc = 0.0;
    for (int l = 0; l < NLEV; ++l) acc += s_loss[l];
    out[0] = (float)(acc / (double)NLEV);
  }
}

extern "C" void kernel_launch(void* const* d_in, const int* in_sizes, int n_in,
                              void* d_out, int out_size, void* d_ws,
                              size_t ws_size, hipStream_t stream) {
  const float* h0 = (const float*)d_in[0];
  const float* h1 = (const float*)d_in[1];
  const float* h2 = (const float*)d_in[2];
  const float* h3 = (const float*)d_in[3];
  const float* h4 = (const float*)d_in[4];
  const float* boxes = (const float*)d_in[5];
  const int* dimx = (const int*)d_in[6];
  const int* dimy = (const int*)d_in[7];

  fused_kernel<<<NBLOCKS, 256, 0, stream>>>(h0, h1, h2, h3, h4, boxes, dimx,
                                            dimy, d_ws);
  final_kernel<<<1, 320, 0, stream>>>(d_ws, (float*)d_out);
}